// Round 12
// baseline (23716.512 us; speedup 1.0000x reference)
//
#include <hip/hip_runtime.h>

#define Bdim 128
#define Tdim 256
#define Hdim 512
#define INdim 300
#define KXdim 320
#define NC 45
#define NTHR 256

typedef _Float16 h16;
typedef __attribute__((ext_vector_type(8))) _Float16 half8;
typedef __attribute__((ext_vector_type(4))) float float4v;
typedef unsigned long long u64;

// ---------------- prep1: W0 = Wemb @ Wx0 (fp32), cb fused biases ----------------
__global__ __launch_bounds__(NTHR) void prep1_kernel(
    const float* Wemb, const float* bemb,
    const float* Wx_l2r, const float* bx_l2r, const float* bh_l2r,
    const float* Wx_r2l, const float* bx_r2l, const float* bh_r2l,
    float* W0, float* cb)
{
    int gid = blockIdx.x * NTHR + threadIdx.x;
    const int nW0 = 2 * KXdim * Hdim;
    if (gid < nW0) {
        int dir = gid / (KXdim * Hdim);
        int rem = gid % (KXdim * Hdim);
        int i = rem / Hdim, h = rem % Hdim;
        const float* Wx = dir ? Wx_r2l : Wx_l2r;
        float s = 0.f;
        if (i < INdim) {
            for (int k = 0; k < Hdim; ++k)
                s += Wemb[i * Hdim + k] * Wx[k * Hdim + h];
        }
        W0[gid] = s;
    } else {
        int idx = gid - nW0;
        if (idx < 2 * 3 * Hdim) {
            int dir = idx / (3 * Hdim);
            int l = (idx / Hdim) % 3;
            int h = idx % Hdim;
            const float* Wx = dir ? Wx_r2l : Wx_l2r;
            const float* bx = dir ? bx_r2l : bx_l2r;
            const float* bh = dir ? bh_r2l : bh_l2r;
            float s = bx[l * Hdim + h] + bh[l * Hdim + h];
            if (l == 0) {
                for (int k = 0; k < Hdim; ++k)
                    s += bemb[k] * Wx[k * Hdim + h];
            }
            cb[idx] = s;
        }
    }
}

// ---------------- pack_W: fp16 B-frag layout [u][cs16][ks32][nt2][lane64][j8] ----
__global__ __launch_bounds__(NTHR) void pack_W_kernel(
    const float* W0,
    const float* Wx_l2r, const float* Wh_l2r,
    const float* Wx_r2l, const float* Wh_r2l,
    h16* Wfrag)
{
    int e = blockIdx.x * NTHR + threadIdx.x;
    if (e >= 6 * 16 * 32 * 2 * 64 * 8) return;
    int j    = e & 7;
    int lane = (e >> 3) & 63;
    int nt   = (e >> 9) & 1;
    int ks   = (e >> 10) & 31;
    int cs   = (e >> 15) & 15;
    int u    = e >> 19;
    int dir = u / 3, l = u % 3;
    int n  = cs * 32 + nt * 16 + (lane & 15);
    int kk = ks * 32 + ((lane >> 4) * 8) + j;
    float v;
    if (kk < 512) {
        if (l == 0) {
            v = (kk < KXdim) ? W0[(dir * KXdim + kk) * Hdim + n] : 0.f;
        } else {
            const float* Wx = dir ? Wx_r2l : Wx_l2r;
            v = Wx[(l * Hdim + kk) * Hdim + n];
        }
    } else {
        const float* Wh = dir ? Wh_r2l : Wh_l2r;
        v = Wh[(l * Hdim + (kk - 512)) * Hdim + n];
    }
    Wfrag[e] = (h16)v;
}

// ---------------- pack_W0f: fp16 B-frags of W0 for zx0 kernel --------------------
__global__ __launch_bounds__(NTHR) void pack_W0f_kernel(const float* W0, h16* W0f)
{
    int e = blockIdx.x * NTHR + threadIdx.x;
    if (e >= 2 * 32 * 10 * 64 * 8) return;
    int j    = e & 7;
    int lane = (e >> 3) & 63;
    int rest = e >> 9;
    int ks   = rest % 10;
    rest /= 10;
    int nt   = rest & 31;
    int dir  = rest >> 5;
    int k = ks * 32 + ((lane >> 4) * 8) + j;
    int n = nt * 16 + (lane & 15);
    W0f[e] = (h16)W0[(dir * KXdim + k) * Hdim + n];
}

// ---------------- zx0: zx0f[dir][t][nt32][mt8][lane64][reg4] fp16 ----------------
__global__ __launch_bounds__(NTHR) void zx0_kernel(
    const float* __restrict__ x0, const float* __restrict__ x1,
    const h16* __restrict__ W0f, const float* __restrict__ cb,
    h16* __restrict__ zx0f)
{
    int bx = blockIdx.x;
    int t = bx & 255, mh = (bx >> 8) & 1, dir = bx >> 9;
    const int tid = threadIdx.x;
    __shared__ h16 xl[64 * 328];
    const float* xs = dir ? x1 : x0;
    for (int i = tid; i < 64 * 328; i += NTHR) {
        int r = i / 328, k = i - r * 328;
        int b = mh * 64 + r;
        float v = (k < INdim) ? xs[(b * Tdim + t) * INdim + k] : 0.f;
        xl[i] = (h16)v;
    }
    __syncthreads();
    int wave = tid >> 6, lane = tid & 63;
    int r15 = lane & 15, q = lane >> 4;
    for (int nt = 0; nt < 32; ++nt) {
        float4v acc = {0.f, 0.f, 0.f, 0.f};
        #pragma unroll
        for (int ks = 0; ks < 10; ++ks) {
            half8 af = *(const half8*)&xl[(wave * 16 + r15) * 328 + ks * 32 + q * 8];
            half8 bf = *(const half8*)&W0f[(((dir * 32 + nt) * 10 + ks) * 64 + lane) * 8];
            acc = __builtin_amdgcn_mfma_f32_16x16x32_f16(af, bf, acc, 0, 0, 0);
        }
        int col = nt * 16 + r15;
        float cbv = cb[(dir * 3 + 0) * Hdim + col];
        union { h16 h[4]; uint2 u2; } o;
        #pragma unroll
        for (int r = 0; r < 4; ++r) o.h[r] = (h16)(acc[r] + cbv);
        h16* dst = zx0f + (((( (size_t)dir * Tdim + t) * 32 + nt) * 8 + (mh * 4 + wave)) * 64 + lane) * 4;
        *(uint2*)dst = o.u2;
    }
}

// ---------------- main pipeline: batch-parallel, block-LOCAL recurrence ----------
// 16 INDEPENDENT blocks (2 dirs x 8 row-groups of 16 batch rows), 512 threads
// (8 waves; wave w owns cols w*64..w*64+63). All 3 layers per step in-block:
// h tiles in LDS (row pad 520 -> 2-way-free banks); weights streamed from
// global per step (B-frag layout; cacheable loads, per-XCD L2 holds one dir's
// 3MB); LN via LDS reduce; tanh once per element. NO inter-block sync, NO
// cooperative launch, NO coherent atomics. 512thr (not R6's 1024) -> 256-VGPR
// budget so the fully-unrolled ks loops keep 16+ weight loads in flight
// (R6's failure: VGPR=64 -> latency-bound weight stream at 270GB/s).
__global__ __launch_bounds__(512, 2) void rnn_pipe(
    const h16* __restrict__ Wfrag, const h16* __restrict__ zx0f,
    const float* __restrict__ cb, const float* __restrict__ lng,
    const float* __restrict__ lnb, h16* __restrict__ h2)
{
    const int tid = threadIdx.x;
    const int w = tid >> 6, lane = tid & 63;
    const int r15 = lane & 15, quad = lane >> 4;
    const int blk = blockIdx.x;
    const int dir = (blk >> 2) & 1;                 // blk%8 fixes dir (XCD heuristic)
    const int rg  = (blk & 3) | ((blk >> 3) << 2);  // 0..7 row group (16 rows each)

    __shared__ h16 ht[3][16 * 520];     // h0,h1,h2 tiles; row stride 520 (1040B)
    __shared__ float sred[8][16], qred[8][16];
    __shared__ float mr[16][2];         // rstd, -m*rstd per row

    {   // zero h tiles (h_init = 0)
        uint4* hp = (uint4*)&ht[0][0];
        for (int i = tid; i < 3120; i += 512) hp[i] = make_uint4(0, 0, 0, 0);
    }

    // weight base pointers (R9-verified Wfrag indexing): frag for (u, ntg, ks)
    // at ((((u*16 + (ntg>>1))*32 + ks)*2 + (ntg&1))*64 + lane)*8; ks stride 1024.
    const h16* wp[3][4];
    float4v g2[3], b2[3], cba[3];
    #pragma unroll
    for (int l = 0; l < 3; ++l) {
        int u = dir * 3 + l;
        #pragma unroll
        for (int n = 0; n < 4; ++n) {
            int ntg = w * 4 + n;
            wp[l][n] = Wfrag + (((size_t)(u * 16 + (ntg >> 1)) * 64 + (ntg & 1)) * 64 + lane) * 8;
            int col = w * 64 + n * 16 + r15;
            g2[l][n] = 2.0f * lng[l * Hdim + col];
            b2[l][n] = 2.0f * lnb[l * Hdim + col];
            cba[l][n] = (l > 0) ? cb[(dir * 3 + l) * Hdim + col] : 0.f;
        }
    }
    __syncthreads();

    // stats + tanh + store h tile (R9-verified LN math / tanh numerics)
    auto lnstore = [&](float4v (&ac)[4], float4v g2v, float4v b2v, h16* dst) {
        float s[4], q[4];
        #pragma unroll
        for (int r = 0; r < 4; ++r) {
            s[r] = ac[0][r] + ac[1][r] + ac[2][r] + ac[3][r];
            q[r] = ac[0][r] * ac[0][r] + ac[1][r] * ac[1][r]
                 + ac[2][r] * ac[2][r] + ac[3][r] * ac[3][r];
            s[r] += __shfl_xor(s[r], 1); q[r] += __shfl_xor(q[r], 1);
            s[r] += __shfl_xor(s[r], 2); q[r] += __shfl_xor(q[r], 2);
            s[r] += __shfl_xor(s[r], 4); q[r] += __shfl_xor(q[r], 4);
            s[r] += __shfl_xor(s[r], 8); q[r] += __shfl_xor(q[r], 8);
        }
        if (r15 == 0) {
            #pragma unroll
            for (int r = 0; r < 4; ++r) {
                sred[w][quad * 4 + r] = s[r];
                qred[w][quad * 4 + r] = q[r];
            }
        }
        __syncthreads();
        if (tid < 16) {
            float ss = 0.f, qq = 0.f;
            #pragma unroll
            for (int ww = 0; ww < 8; ++ww) { ss += sred[ww][tid]; qq += qred[ww][tid]; }
            float m = ss * (1.0f / Hdim);
            float var = qq * (1.0f / Hdim) - m * m;
            float rstd = rsqrtf(var + 1e-5f);
            mr[tid][0] = rstd;
            mr[tid][1] = -m * rstd;
        }
        __syncthreads();
        #pragma unroll
        for (int r = 0; r < 4; ++r) {
            int row = quad * 4 + r;
            float A = mr[row][0], C = mr[row][1];
            #pragma unroll
            for (int n = 0; n < 4; ++n) {
                float x2 = __builtin_fmaf(__builtin_fmaf(ac[n][r], A, C), g2v[n], b2v[n]);
                float E = __expf(x2);
                dst[row * 520 + w * 64 + n * 16 + r15] =
                    (h16)(1.0f - __fdividef(2.0f, E + 1.0f));
            }
        }
        __syncthreads();
    };

    for (int t = 0; t < Tdim; ++t) {
        float4v acc[4];
        // ---------------- layer 0: z0 = zx0(t) + h0(t-1) @ Wh0 ----------------
        #pragma unroll
        for (int n = 0; n < 4; ++n) {
            const h16* zp = zx0f +
                ((((size_t)dir * Tdim + t) * 32 + (w * 4 + n)) * 8 + rg) * 256 + lane * 4;
            union { uint2 uu; h16 hh[4]; } v; v.uu = *(const uint2*)zp;
            #pragma unroll
            for (int r = 0; r < 4; ++r) acc[n][r] = (float)v.hh[r];
        }
        #pragma unroll
        for (int ks = 0; ks < 16; ++ks) {
            half8 af = *(const half8*)&ht[0][r15 * 520 + ks * 32 + quad * 8];
            #pragma unroll
            for (int n = 0; n < 4; ++n) {
                half8 bf = *(const half8*)(wp[0][n] + (size_t)(16 + ks) * 1024);
                acc[n] = __builtin_amdgcn_mfma_f32_16x16x32_f16(af, bf, acc[n], 0, 0, 0);
            }
        }
        lnstore(acc, g2[0], b2[0], ht[0]);

        // ---------- layers 1,2: z = h_{l-1}(t) @ Wx + h_l(t-1) @ Wh + cb ----------
        #pragma unroll
        for (int l = 1; l < 3; ++l) {
            #pragma unroll
            for (int n = 0; n < 4; ++n) acc[n] = (float4v){0.f, 0.f, 0.f, 0.f};
            #pragma unroll
            for (int ks = 0; ks < 16; ++ks) {
                half8 af = *(const half8*)&ht[l - 1][r15 * 520 + ks * 32 + quad * 8];
                #pragma unroll
                for (int n = 0; n < 4; ++n) {
                    half8 bf = *(const half8*)(wp[l][n] + (size_t)ks * 1024);
                    acc[n] = __builtin_amdgcn_mfma_f32_16x16x32_f16(af, bf, acc[n], 0, 0, 0);
                }
            }
            #pragma unroll
            for (int ks = 0; ks < 16; ++ks) {
                half8 af = *(const half8*)&ht[l][r15 * 520 + ks * 32 + quad * 8];
                #pragma unroll
                for (int n = 0; n < 4; ++n) {
                    half8 bf = *(const half8*)(wp[l][n] + (size_t)(16 + ks) * 1024);
                    acc[n] = __builtin_amdgcn_mfma_f32_16x16x32_f16(af, bf, acc[n], 0, 0, 0);
                }
            }
            #pragma unroll
            for (int n = 0; n < 4; ++n)
                #pragma unroll
                for (int r = 0; r < 4; ++r) acc[n][r] += cba[l][n];
            lnstore(acc, g2[l], b2[l], ht[l]);
        }

        // ---- h2(t) global write (coalesced, from padded tile) ----
        {
            int row = tid >> 5, ch = tid & 31;
            const h16* sp = &ht[2][row * 520 + ch * 16];
            h16* d2 = h2 + (((size_t)dir * Tdim + t) * Bdim + rg * 16 + row) * Hdim + ch * 16;
            *(uint4*)d2 = *(const uint4*)sp;
            *(uint4*)(d2 + 8) = *(const uint4*)(sp + 8);
        }
    }
}

// ---------------- FC: logits = [h_l2r ; gather(h_r2l)] @ W_fc + b_fc -------------
__global__ __launch_bounds__(NTHR) void fc_kernel(
    const h16* __restrict__ h2, const int* __restrict__ pad,
    const float* __restrict__ Wfc, const float* __restrict__ bfc,
    float* __restrict__ out)
{
    __shared__ float sA[64 * 68];
    __shared__ float sB[64 * 48];
    const int blk = blockIdx.x, tid = threadIdx.x;
    const int b = blk >> 2;
    const int j0 = (blk & 3) * 64;
    const int p = pad[b];
    const int rg = tid >> 4;
    const int c0 = (tid & 15) * 3;
    float acc[4][3] = {};

    for (int k0 = 0; k0 < 2 * Hdim; k0 += 64) {
        {
            int rr = tid >> 2;
            int kp = (tid & 3) * 16;
            int j = j0 + rr;
            const h16* src;
            if (k0 < Hdim) {
                src = h2 + (((size_t)0 * Tdim + j) * Bdim + b) * Hdim + k0 + kp;
            } else {
                int idx = (j < p) ? (p - j - 1) : j;
                src = h2 + (((size_t)1 * Tdim + idx) * Bdim + b) * Hdim + (k0 - Hdim) + kp;
            }
            union { uint4 u4; h16 h[8]; } w0, w1;
            w0.u4 = *(const uint4*)src;
            w1.u4 = *(const uint4*)(src + 8);
            #pragma unroll
            for (int i = 0; i < 8; ++i) {
                sA[rr * 68 + kp + i]     = (float)w0.h[i];
                sA[rr * 68 + kp + 8 + i] = (float)w1.h[i];
            }
        }
        for (int e = tid; e < 64 * 48; e += NTHR) {
            int kk = e / 48, c = e - kk * 48;
            sB[e] = (c < NC) ? Wfc[(k0 + kk) * NC + c] : 0.f;
        }
        __syncthreads();
        for (int kk = 0; kk < 64; ++kk) {
            float b0 = sB[kk * 48 + c0 + 0];
            float b1 = sB[kk * 48 + c0 + 1];
            float b2 = sB[kk * 48 + c0 + 2];
            #pragma unroll
            for (int i = 0; i < 4; ++i) {
                float av = sA[(rg * 4 + i) * 68 + kk];
                acc[i][0] += av * b0; acc[i][1] += av * b1; acc[i][2] += av * b2;
            }
        }
        __syncthreads();
    }
    #pragma unroll
    for (int i = 0; i < 4; ++i) {
        int r = blk * 64 + rg * 4 + i;
        #pragma unroll
        for (int jj = 0; jj < 3; ++jj) {
            int c = c0 + jj;
            if (c < NC) out[r * NC + c] = acc[i][jj] + bfc[c];
        }
    }
}

extern "C" void kernel_launch(void* const* d_in, const int* in_sizes, int n_in,
                              void* d_out, int out_size, void* d_ws, size_t ws_size,
                              hipStream_t stream) {
    const float* x      = (const float*)d_in[0];
    const float* rx     = (const float*)d_in[1];
    const int*   pad    = (const int*)d_in[2];
    const float* Wemb   = (const float*)d_in[4];
    const float* bemb   = (const float*)d_in[5];
    const float* Wx_l2r = (const float*)d_in[6];
    const float* bx_l2r = (const float*)d_in[7];
    const float* Wh_l2r = (const float*)d_in[8];
    const float* bh_l2r = (const float*)d_in[9];
    const float* Wx_r2l = (const float*)d_in[10];
    const float* bx_r2l = (const float*)d_in[11];
    const float* Wh_r2l = (const float*)d_in[12];
    const float* bh_r2l = (const float*)d_in[13];
    const float* lng    = (const float*)d_in[14];
    const float* lnb    = (const float*)d_in[15];
    const float* Wfc    = (const float*)d_in[16];
    const float* bfc    = (const float*)d_in[17];

    char* base = (char*)d_ws;
    size_t off = 0;
    auto alloc = [&](size_t bytes) { char* p = base + off; off += (bytes + 255) & ~(size_t)255; return p; };
    h16*   zx0f  = (h16*)  alloc((size_t)2 * Tdim * 32 * 8 * 64 * 4 * 2);      // 67 MB
    h16*   h2    = (h16*)  alloc((size_t)2 * Tdim * Bdim * Hdim * 2);          // 67 MB
    h16*   Wfrag = (h16*)  alloc((size_t)6 * 16 * 32768 * 2);                  // 6.3 MB
    h16*   W0f   = (h16*)  alloc((size_t)2 * 32 * 10 * 64 * 8 * 2);            // 0.66 MB
    float* W0    = (float*)alloc((size_t)2 * KXdim * Hdim * 4);
    float* cb    = (float*)alloc((size_t)2 * 3 * Hdim * 4);

    prep1_kernel<<<(2 * KXdim * Hdim + 2 * 3 * Hdim) / NTHR, NTHR, 0, stream>>>(
        Wemb, bemb, Wx_l2r, bx_l2r, bh_l2r, Wx_r2l, bx_r2l, bh_r2l, W0, cb);

    pack_W_kernel<<<(6 * 16 * 32 * 2 * 64 * 8) / NTHR, NTHR, 0, stream>>>(
        W0, Wx_l2r, Wh_l2r, Wx_r2l, Wh_r2l, Wfrag);

    pack_W0f_kernel<<<(2 * 32 * 10 * 64 * 8) / NTHR, NTHR, 0, stream>>>(W0, W0f);

    zx0_kernel<<<1024, NTHR, 0, stream>>>(x, rx, W0f, cb, zx0f);

    rnn_pipe<<<dim3(16), dim3(512), 0, stream>>>(Wfrag, zx0f, cb, lng, lnb, h2);

    fc_kernel<<<(Bdim * Tdim) / 64, NTHR, 0, stream>>>(h2, pad, Wfc, bfc, (float*)d_out);
}